// Round 11
// baseline (481.050 us; speedup 1.0000x reference)
//
#include <hip/hip_runtime.h>
#include <hip/hip_bf16.h>

#define S_LEN 2048
#define NHEAD 16
#define NOPE 128
#define ROPE 64
#define HD 192   // nope + rope

typedef unsigned short ushort_t;
typedef __attribute__((ext_vector_type(8))) short short8;
typedef __attribute__((ext_vector_type(4))) float f32x4;

#define AS1 __attribute__((address_space(1)))
#define AS3 __attribute__((address_space(3)))

__device__ __forceinline__ unsigned short f2bf(float f) {
  unsigned int u = __float_as_uint(f);
  return (unsigned short)((u + 0x7FFFu + ((u >> 16) & 1u)) >> 16);
}

// ---------------- fused prep: cast x -> bf16  +  5x transpose_cast ----------------
__global__ __launch_bounds__(256) void prep_k(const float* __restrict__ x, ushort_t* __restrict__ xb,
                                              const float* __restrict__ wd_q, ushort_t* __restrict__ wdqt,
                                              const float* __restrict__ wd_kv, ushort_t* __restrict__ wdkvt,
                                              const float* __restrict__ wu_q, ushort_t* __restrict__ wuqt,
                                              const float* __restrict__ wu_kv, ushort_t* __restrict__ wukvt,
                                              const float* __restrict__ wo, ushort_t* __restrict__ wot) {
  int id = blockIdx.x;
  if (id < 4096) {
    const int i = id * 256 + threadIdx.x;
    const float4 v0 = *(const float4*)&x[(size_t)i * 8];
    const float4 v1 = *(const float4*)&x[(size_t)i * 8 + 4];
    union { uint4 u; ushort_t s[8]; } pk;
    pk.s[0] = f2bf(v0.x); pk.s[1] = f2bf(v0.y); pk.s[2] = f2bf(v0.z); pk.s[3] = f2bf(v0.w);
    pk.s[4] = f2bf(v1.x); pk.s[5] = f2bf(v1.y); pk.s[6] = f2bf(v1.z); pk.s[7] = f2bf(v1.w);
    *(uint4*)&xb[(size_t)i * 8] = pk.u;
    return;
  }
  id -= 4096;
  const float* B; ushort_t* Bt; int K, N, gx;
  if (id < 3072)               { B = wd_q;  Bt = wdqt;  K = 2048; N = 1536; gx = 48;  }
  else if ((id -= 3072) < 1280){ B = wd_kv; Bt = wdkvt; K = 2048; N = 576;  gx = 20;  }
  else if ((id -= 1280) < 4608){ B = wu_q;  Bt = wuqt;  K = 1536; N = 3072; gx = 96;  }
  else if ((id -= 4608) < 2048){ B = wu_kv; Bt = wukvt; K = 512;  N = 4096; gx = 128; }
  else { id -= 2048;             B = wo;    Bt = wot;   K = 2048; N = 2048; gx = 64;  }
  __shared__ float tile[32][33];
  const int tx = threadIdx.x & 31, ty = threadIdx.x >> 5;  // 32 x 8
  const int n0 = (id % gx) * 32, k0 = (id / gx) * 32;
  if (n0 >= N) {
#pragma unroll
    for (int r = 0; r < 4; ++r)
      Bt[(size_t)(n0 + ty + 8 * r) * K + k0 + tx] = 0;
    return;
  }
#pragma unroll
  for (int r = 0; r < 4; ++r)
    tile[ty + 8 * r][tx] = B[(size_t)(k0 + ty + 8 * r) * N + n0 + tx];
  __syncthreads();
#pragma unroll
  for (int r = 0; r < 4; ++r)
    Bt[(size_t)(n0 + ty + 8 * r) * K + k0 + tx] = f2bf(tile[tx][ty + 8 * r]);
}

// ---------------- MFMA GEMM: 512 thr / 8 waves / 128x128 tile --------------------
// Round 11: triple-buffered LDS, prefetch depth 2 — at step ks the wait covers
// loads issued two compute phases earlier (~2x the latency cover of round 9's
// 1-deep), at 48 KB LDS (keeps 3 blocks/CU; m132's 64KB occupancy cliff avoided).
// trb (V-transpose) aliased onto dead As. EPI=4: fused qup+kvu routing (two
// independent GEMMs in one launch to overlap dispatch tails).
// EPI=0: f32 C.  EPI=1: KV split.  EPI=2: down-proj routing.  EPI=3: q-up RoPE.
template<int EPI>
__global__ __launch_bounds__(512, 4) void mfma_gemm(const ushort_t* __restrict__ A,
                                                 const ushort_t* __restrict__ Bt,
                                                 float* __restrict__ C,
                                                 int M, int N, int K, int ldc,
                                                 ushort_t* __restrict__ kb16o,
                                                 ushort_t* __restrict__ vto,
                                                 float* __restrict__ C2,
                                                 const float* __restrict__ cosb,
                                                 const float* __restrict__ sinb,
                                                 const ushort_t* __restrict__ A2,
                                                 const ushort_t* __restrict__ Bt2,
                                                 ushort_t* __restrict__ kb2) {
  __shared__ __align__(16) ushort_t As[3][128 * 32];   // 24 KB
  __shared__ __align__(16) ushort_t Bs[3][128 * 32];   // 24 KB
  const int tid = threadIdx.x;
  const int lane = tid & 63;
  const int wave = tid >> 6;        // 0..7
  const int wm = wave & 3, wn = wave >> 2;   // 4 m-strips x 2 n-strips

  const ushort_t* Ax;
  const ushort_t* Btx;
  int Kx;
  bool isq = true;
  int m0, n0;
  if constexpr (EPI == 4) {
    int flat = blockIdx.x;                     // 1792 blocks
    flat = (flat & 7) * 224 + (flat >> 3);     // XCD-bijective swizzle
    isq = flat < 768;
    int bxl, byl;
    if (isq) { bxl = flat % 24;  byl = flat / 24;  Ax = A;  Btx = Bt;  Kx = 1536; }
    else     { int f = flat - 768; bxl = f % 32; byl = f / 32; Ax = A2; Btx = Bt2; Kx = 512; }
    m0 = byl * 128; n0 = bxl * 128;
  } else {
    unsigned bxu = blockIdx.x, byu = blockIdx.y;
    const unsigned gx = gridDim.x;
    const unsigned nwg = gx * gridDim.y;
    if ((nwg & 7u) == 0u) {
      unsigned flat = byu * gx + bxu;
      const unsigned cpx = nwg >> 3;
      flat = (flat & 7u) * cpx + (flat >> 3);
      bxu = flat % gx; byu = flat / gx;
    }
    m0 = byu * 128; n0 = bxu * 128;
    Ax = A; Btx = Bt; Kx = K;
  }
  const int l15 = lane & 15, quad = lane >> 4;

  f32x4 acc[2][4] = {};

  const int ma0 = tid >> 2;                                  // row 0..127
  const int scol = (((tid & 3) ^ ((tid >> 3) & 3)) << 3);    // swizzled src col (shorts)
  const int rsw = (l15 >> 1) & 3;                            // read-side slot XOR

  typedef AS3 ushort_t lds_us;
  lds_us* AsL = (lds_us*)As;
  lds_us* BsL = (lds_us*)Bs;
  const int wbase = wave * 512;   // shorts: 64 lanes * 8 shorts

  auto issue = [&](int k0, int buf) {
    __builtin_amdgcn_global_load_lds(
        (const AS1 void*)&Ax[(size_t)(m0 + ma0) * Kx + k0 + scol],
        (AS3 void*)(AsL + buf * 4096 + wbase), 16, 0, 0);
    __builtin_amdgcn_global_load_lds(
        (const AS1 void*)&Btx[(size_t)(n0 + ma0) * Kx + k0 + scol],
        (AS3 void*)(BsL + buf * 4096 + wbase), 16, 0, 0);
  };

  const int nk = Kx >> 5;
  issue(0, 0);
  issue(32, 1);
  __builtin_amdgcn_sched_barrier(0);

  int buf = 0;
  for (int ks = 0; ks < nk; ++ks) {
    if (ks + 2 < nk) {
      int b2 = buf + 2; if (b2 >= 3) b2 -= 3;
      issue((ks + 2) << 5, b2);           // 2-deep: lands two phases from now
      __builtin_amdgcn_sched_barrier(0);
      asm volatile("s_waitcnt vmcnt(4)" ::: "memory");   // current buf complete
    } else if (ks + 1 < nk) {
      asm volatile("s_waitcnt vmcnt(2)" ::: "memory");
    } else {
      asm volatile("s_waitcnt vmcnt(0)" ::: "memory");
    }
    __builtin_amdgcn_s_barrier();
    __builtin_amdgcn_sched_barrier(0);

    short8 af[2], bf[4];
#pragma unroll
    for (int i = 0; i < 2; ++i)
      af[i] = *(const short8*)&As[buf][(wm * 32 + i * 16 + l15) * 32 + ((quad ^ rsw) << 3)];
#pragma unroll
    for (int j = 0; j < 4; ++j)
      bf[j] = *(const short8*)&Bs[buf][(wn * 64 + j * 16 + l15) * 32 + ((quad ^ rsw) << 3)];
    __builtin_amdgcn_s_setprio(1);
#pragma unroll
    for (int i = 0; i < 2; ++i)
#pragma unroll
      for (int j = 0; j < 4; ++j)
        acc[i][j] = __builtin_amdgcn_mfma_f32_16x16x32_bf16(af[i], bf[j], acc[i][j], 0, 0, 0);
    __builtin_amdgcn_s_setprio(0);
    __builtin_amdgcn_s_barrier();     // all waves done with buf (rewritten at ks+3)
    __builtin_amdgcn_sched_barrier(0);
    ++buf; if (buf == 3) buf = 0;
  }

  // ---------------- epilogues ----------------
  if constexpr (EPI == 0) {
#pragma unroll
    for (int i = 0; i < 2; ++i)
#pragma unroll
      for (int r = 0; r < 4; ++r) {
        const size_t rg = (size_t)(m0 + wm * 32 + i * 16 + quad * 4 + r);
#pragma unroll
        for (int j = 0; j < 4; ++j)
          C[rg * ldc + n0 + wn * 64 + j * 16 + l15] = acc[i][j][r];
      }
  } else if constexpr (EPI == 2) {
    float* Cd;
    int ldd, nc;
    if (n0 < 1536) { Cd = C;  ldd = 1536; nc = n0; }
    else           { Cd = C2; ldd = 640;  nc = n0 - 1536; }
#pragma unroll
    for (int i = 0; i < 2; ++i)
#pragma unroll
      for (int r = 0; r < 4; ++r) {
        const size_t rg = (size_t)(m0 + wm * 32 + i * 16 + quad * 4 + r);
#pragma unroll
        for (int j = 0; j < 4; ++j)
          Cd[rg * ldd + nc + wn * 64 + j * 16 + l15] = acc[i][j][r];
      }
  } else if constexpr (EPI == 4) {
    if (isq) {
      // q-up epilogue: scale + RoPE + bf16 -> kb16o (q16)
      const float qscale = 0.07216878364870323f;  // 1/sqrt(192)
#pragma unroll
      for (int i = 0; i < 2; ++i)
#pragma unroll
        for (int r = 0; r < 4; ++r) {
          const int rg = m0 + wm * 32 + i * 16 + quad * 4 + r;
          const int sp = rg & (S_LEN - 1);
#pragma unroll
          for (int j = 0; j < 4; ++j) {
            const int col = n0 + wn * 64 + j * 16 + l15;
            float val = acc[i][j][r] * qscale;
            const float pr = __shfl_xor(val, 1);   // adjacent column (same row)
            const int dd = col % HD;               // 0..191 within head
            float o = val;
            if (dd >= NOPE) {
              const int d = (dd - NOPE) >> 1;
              const float cc = cosb[sp * 32 + d];
              const float sn = sinb[sp * 32 + d];
              o = (lane & 1) ? (pr * sn + val * cc) : (val * cc - pr * sn);
            }
            kb16o[(size_t)rg * 3072 + col] = f2bf(o);
          }
        }
    } else {
      // kvu split epilogue: K rows bf16 (kb2) + V transpose (vto)
      const int h = n0 >> 8;
      const bool is_v = (n0 >> 7) & 1;
      if (!is_v) {
#pragma unroll
        for (int i = 0; i < 2; ++i)
#pragma unroll
          for (int r = 0; r < 4; ++r) {
            const size_t rg = (size_t)(m0 + wm * 32 + i * 16 + quad * 4 + r);
#pragma unroll
            for (int j = 0; j < 4; ++j)
              kb2[rg * 2048 + h * 128 + wn * 64 + j * 16 + l15] = f2bf(acc[i][j][r]);
          }
      } else {
        ushort_t* trb = (ushort_t*)&As[0][0];   // 17 KB aliased onto dead As
        const int bb = m0 >> 11;
        const int m0loc = m0 & 2047;
        ushort_t* vbase = vto + ((size_t)(bb * NHEAD + h) * 128) * 2048;
#pragma unroll
        for (int vh = 0; vh < 2; ++vh) {
          if (wn == vh) {
#pragma unroll
            for (int i = 0; i < 2; ++i)
#pragma unroll
              for (int r = 0; r < 4; ++r) {
                const int tloc = wm * 32 + i * 16 + quad * 4 + r;   // 0..127
#pragma unroll
                for (int j = 0; j < 4; ++j)
                  trb[(j * 16 + l15) * 136 + tloc] = f2bf(acc[i][j][r]);
              }
          }
          __syncthreads();
#pragma unroll
          for (int it = 0; it < 2; ++it) {
            const int u = tid + (it << 9);
            const int vdl = u >> 4, tc = u & 15;
            *(uint4*)&vbase[(size_t)(vh * 64 + vdl) * 2048 + m0loc + tc * 8] =
                *(const uint4*)&trb[vdl * 136 + tc * 8];
          }
          __syncthreads();
        }
      }
    }
  }
}

// ---------------- merged RMSNorm (+ fused k-rope on kv rows) ----------------
__global__ __launch_bounds__(256) void rmsnorm2_k(const float* __restrict__ cq,
                                                  ushort_t* __restrict__ cqn,
                                                  const float* __restrict__ qw,
                                                  const float* __restrict__ kvd,
                                                  ushort_t* __restrict__ ckvn,
                                                  const float* __restrict__ kvw,
                                                  ushort_t* __restrict__ krope16,
                                                  const float* __restrict__ cosb,
                                                  const float* __restrict__ sinb) {
  const bool is_q = blockIdx.x < 4096;
  const int row = blockIdx.x & 4095;
  const int tid = threadIdx.x;
  const float* ip = is_q ? cq + (size_t)row * 1536 : kvd + (size_t)row * 640;
  ushort_t* op = is_q ? cqn + (size_t)row * 1536 : ckvn + (size_t)row * 512;
  const float* w = is_q ? qw : kvw;
  const int L = is_q ? 1536 : 512;
  const int nper = L >> 8;
  float r[6];
  float ss = 0.f;
  for (int j = 0; j < nper; ++j) {
    r[j] = ip[tid + (j << 8)];
    ss += r[j] * r[j];
  }
  for (int off = 32; off; off >>= 1) ss += __shfl_down(ss, off);
  __shared__ float wsum[4];
  __shared__ float scale_s;
  if ((tid & 63) == 0) wsum[tid >> 6] = ss;
  __syncthreads();
  if (tid == 0) {
    float t = wsum[0] + wsum[1] + wsum[2] + wsum[3];
    scale_s = rsqrtf(t / (float)L + 1e-5f);
  }
  __syncthreads();
  const float sc = scale_s;
  for (int j = 0; j < nper; ++j)
    op[tid + (j << 8)] = f2bf(r[j] * sc * w[tid + (j << 8)]);
  if (!is_q && tid < 32) {           // fused k-rope (kvd cols 512..639)
    const int d = tid;
    const int s = row & (S_LEN - 1);
    const float c = cosb[s * 32 + d];
    const float sn = sinb[s * 32 + d];
    const float* kb = kvd + (size_t)row * 640 + 512;
    const float y0 = kb[2 * d], y1 = kb[2 * d + 1];
    union { unsigned int u; ushort_t s2[2]; } pk;
    pk.s2[0] = f2bf(y0 * c - y1 * sn);
    pk.s2[1] = f2bf(y0 * sn + y1 * c);
    *(unsigned int*)&krope16[(size_t)row * 64 + 2 * d] = pk.u;
  }
}

// ---------------- MFMA flash attention (unchanged from round 10) ----------------
#define QT 128
#define KC 64
__global__ __launch_bounds__(1024, 4) void attn_k(const ushort_t* __restrict__ q16,
                                                  const ushort_t* __restrict__ kb16,
                                                  const ushort_t* __restrict__ vT,
                                                  const ushort_t* __restrict__ krope16,
                                                  ushort_t* __restrict__ outp) {
  const int bx = blockIdx.x;
  const int g = bx & 31;            // (b,h) group -> XCD g%8
  const int s = bx >> 5;            // slot 0..15
  const int tile = (s < 8) ? s : 23 - s;
  const int b = g >> 4, h = g & 15;
  const int q0 = tile * QT;
  const int tid = threadIdx.x;      // 0..1023
  const int lane = tid & 63;
  const int wv = tid >> 6;          // 0..15
  const int wg = wv >> 3;           // chunk-group 0/1
  const int wq8 = wv & 7;           // q-strip within tile
  const int gtid = tid & 511;       // thread id within group
  const int l15 = lane & 15, quad = lane >> 4;

  __shared__ __align__(16) ushort_t Kn[2][64 * 128];     // 32 KB
  __shared__ __align__(16) ushort_t Kr[2][64 * 64];      // 16 KB
  __shared__ __align__(16) ushort_t Vt[2][2][128 * 64];  // 64 KB (per-group dbuf)
  __shared__ __align__(16) ushort_t Pb[16][16 * 72];     // 36 KB

  const int qbase = q0 + wq8 * 16;  // wave's 16 q-rows
  const size_t growq = (size_t)b * S_LEN + qbase;
  const ushort_t* vTh = vT + ((size_t)(b * NHEAD + h) * 128) * 2048;
  const size_t bbase = (size_t)b * S_LEN;

  typedef AS3 ushort_t lds_us;
  lds_us* KnL = (lds_us*)Kn;
  lds_us* KrL = (lds_us*)Kr;
  lds_us* VtL = (lds_us*)Vt;

  auto issueK = [&](int c) {
    const size_t growk = bbase + (size_t)c * KC;
#pragma unroll
    for (int it = 0; it < 2; ++it) {
      const int u = gtid + (it << 9);
      const int key = u >> 4, sl = u & 15;
      const int ss = sl ^ (key & 7);
      __builtin_amdgcn_global_load_lds(
          (const AS1 void*)&kb16[(growk + key) * 2048 + h * 128 + ss * 8],
          (AS3 void*)(KnL + wg * 8192 + it * 4096 + wq8 * 512), 16, 0, 0);
    }
    {
      const int u = gtid;
      const int key = u >> 3, sl = u & 7;
      const int ss = sl ^ (key & 7);
      __builtin_amdgcn_global_load_lds(
          (const AS1 void*)&krope16[(growk + key) * 64 + ss * 8],
          (AS3 void*)(KrL + wg * 4096 + wq8 * 512), 16, 0, 0);
    }
  };
  auto issueV = [&](int c, int buf) {
    const int j0 = c * KC;
#pragma unroll
    for (int it = 0; it < 2; ++it) {
      const int u = gtid + (it << 9);
      const int vd = u >> 3, sl = u & 7;
      const int ss = sl ^ (vd & 7);
      __builtin_amdgcn_global_load_lds(
          (const AS1 void*)&vTh[(size_t)vd * 2048 + j0 + ss * 8],
          (AS3 void*)(VtL + (wg * 2 + buf) * 8192 + it * 4096 + wq8 * 512), 16, 0, 0);
    }
  };

  const int nchunk = (q0 + QT) / KC;   // 2(tile+1), always even
  const int half = nchunk >> 1;        // tile+1 chunks per group
  const int cbase = wg * half;

  // ---- prologue ----
  issueK(cbase);
  issueV(cbase, 0);
  __builtin_amdgcn_sched_barrier(0);

  short8 qf[6];
#pragma unroll
  for (int ks = 0; ks < 6; ++ks)
    qf[ks] = *(const short8*)&q16[(growq + l15) * 3072 + h * HD + ks * 32 + quad * 8];

  f32x4 oacc[8] = {};
  float mrow[4], lrow[4];
  int q_r[4];
#pragma unroll
  for (int r = 0; r < 4; ++r) {
    mrow[r] = -1e30f; lrow[r] = 0.f;
    q_r[r] = qbase + quad * 4 + r;
  }

  asm volatile("s_waitcnt vmcnt(2)" ::: "memory");   // K(c0) landed (V may fly)
  __builtin_amdgcn_s_barrier();
  __builtin_amdgcn_sched_barrier(0);

  for (int cl = 0; cl < half; ++cl) {
    const int c = cbase + cl;
    const int j0 = c * KC;
    const bool more = (cl + 1 < half);
    const int buf = cl & 1;
    const bool skipw = (j0 > qbase + 15);   // chunk fully above diagonal for this wave

    // ---- QK^T on K(c) ----
    f32x4 sacc[4] = {};
    if (!skipw) {
      __builtin_amdgcn_s_setprio(1);
#pragma unroll
      for (int ks = 0; ks < 6; ++ks) {
        short8 kf[4];
        if (ks < 4) {
#pragma unroll
          for (int kt = 0; kt < 4; ++kt)
            kf[kt] = *(const short8*)&Kn[wg][(kt * 16 + l15) * 128 + (((ks * 4 + quad) ^ (l15 & 7)) << 3)];
        } else {
#pragma unroll
          for (int kt = 0; kt < 4; ++kt)
            kf[kt] = *(const short8*)&Kr[wg][(kt * 16 + l15) * 64 + ((((ks - 4) * 4 + quad) ^ (l15 & 7)) << 3)];
        }
#pragma unroll
        for (int kt = 0; kt < 4; ++kt)
          sacc[kt] = __builtin_amdgcn_mfma_f32_16x16x32_bf16(qf[ks], kf[kt], sacc[kt], 0, 0, 0);
      }
      __builtin_amdgcn_s_setprio(0);
    }

    __builtin_amdgcn_s_barrier();          // all waves done reading their Kn/Kr
    if (more) issueK(c + 1);               // DMA into own group's Kn/Kr
    __builtin_amdgcn_sched_barrier(0);

    if (!skipw) {
      if (j0 + KC - 1 > qbase) {           // diagonal chunk: mask
#pragma unroll
        for (int kt = 0; kt < 4; ++kt) {
          const int key = j0 + kt * 16 + l15;
#pragma unroll
          for (int r = 0; r < 4; ++r)
            sacc[kt][r] = (key <= q_r[r]) ? sacc[kt][r] : -1e30f;
        }
      }
      float pmax[4];
#pragma unroll
      for (int r = 0; r < 4; ++r) {
        float mx = fmaxf(fmaxf(sacc[0][r], sacc[1][r]),
                         fmaxf(sacc[2][r], sacc[3][r]));
        mx = fmaxf(mx, __shfl_xor(mx, 1));
        mx = fmaxf(mx, __shfl_xor(mx, 2));
        mx = fmaxf(mx, __shfl_xor(mx, 4));
        mx = fmaxf(mx, __shfl_xor(mx, 8));
        pmax[r] = mx;
      }
      bool need = false;
#pragma unroll
      for (int r = 0; r < 4; ++r)
        need = need || (pmax[r] > mrow[r] + 8.0f);
      const bool upd = __any(need);
      float alpha[4];
      if (upd) {
#pragma unroll
        for (int r = 0; r < 4; ++r) {
          const float mn = fmaxf(mrow[r], pmax[r]);
          alpha[r] = __expf(mrow[r] - mn);
          mrow[r] = mn;
        }
      }
#pragma unroll
      for (int kt = 0; kt < 4; ++kt)
#pragma unroll
        for (int r = 0; r < 4; ++r)
          sacc[kt][r] = __expf(sacc[kt][r] - mrow[r]);
#pragma unroll
      for (int r = 0; r < 4; ++r) {
        float rs = sacc[0][r] + sacc[1][r] + sacc[2][r] + sacc[3][r];
        rs += __shfl_xor(rs, 1);
        rs += __shfl_xor(rs, 2);
        rs += __shfl_xor(rs, 4);
        rs += __shfl_xor(rs, 8);
        lrow[r] = upd ? lrow[r] * alpha[r] + rs : lrow[r] + rs;
      }
#pragma unroll
      for (int kt = 0; kt < 4; ++kt)
#pragma unroll
        for (int r = 0; r < 4; ++r)
          Pb[wv][(quad * 4 + r) * 72 + kt * 16 + l15] = f2bf(sacc[kt][r]);
      if (upd) {
#pragma unroll
        for (int nt = 0; nt < 8; ++nt)
#pragma unroll
          for (int r = 0; r < 4; ++r)
            oacc[nt][r] *= alpha[r];
      }
    }

    if (more) asm volatile("s_waitcnt vmcnt(3)" ::: "memory");  // V(c) landed; K(c+1) flying
    else      asm volatile("s_waitcnt vmcnt(0)" ::: "memory");
    __builtin_amdgcn_s_barrier();          // Vt[wg][buf] visible
    __builtin_amdgcn_sched_barrier(0);

    // ---- PV on Vt[wg][buf] ----
    if (!skipw) {
      __builtin_amdgcn_s_setprio(1);
#pragma unroll
      for (int st = 0; st < 2; ++st) {
        const short8 pf = *(const short8*)&Pb[wv][l15 * 72 + st * 32 + quad * 8];
#pragma unroll
        for (int nt = 0; nt < 8; ++nt) {
          const short8 vf = *(const short8*)&Vt[wg][buf][(nt * 16 + l15) * 64 + (((st * 4 + quad) ^ (l15 & 7)) << 3)];
          oacc[nt] = __builtin_amdgcn_mfma_f32_16x16x32_bf16(pf, vf, oacc[nt], 0, 0, 0);
        }
      }
      __builtin_amdgcn_s_setprio(0);
    }

    if (more) {
      issueV(c + 1, buf ^ 1);              // other buffer; no barrier needed
      __builtin_amdgcn_sched_barrier(0);
      asm volatile("s_waitcnt vmcnt(2)" ::: "memory");  // K(c+1) landed; V(c+1) flying
      __builtin_amdgcn_s_barrier();        // K(c+1) visible
      __builtin_amdgcn_sched_barrier(0);
    }
  }

  // ---- combine group 1 into group 0 (reuse K/V LDS; all DMA/PV complete) ----
  __builtin_amdgcn_s_barrier();
  float* Ocmb = (float*)&Vt[0][0][0];      // 64 KB = 8 strips x 16 rows x 128 f32
  float* Mlb  = (float*)&Kn[0][0];         // (m,l) per row
  if (wg == 1) {
#pragma unroll
    for (int nt = 0; nt < 8; ++nt)
#pragma unroll
      for (int r = 0; r < 4; ++r)
        Ocmb[(size_t)(wq8 * 16 + quad * 4 + r) * 128 + nt * 16 + l15] = oacc[nt][r];
    if (l15 == 0) {
#pragma unroll
      for (int r = 0; r < 4; ++r) {
        Mlb[(wq8 * 16 + quad * 4 + r) * 2 + 0] = mrow[r];
        Mlb[(wq8 * 16 + quad * 4 + r) * 2 + 1] = lrow[r];
      }
    }
  }
  __builtin_amdgcn_s_barrier();
  if (wg == 0) {
#pragma unroll
    for (int r = 0; r < 4; ++r) {
      const int row = wq8 * 16 + quad * 4 + r;
      const float m1 = Mlb[row * 2 + 0];
      const float l1 = Mlb[row * 2 + 1];
      const float mx = fmaxf(mrow[r], m1);
      const float w0 = __expf(mrow[r] - mx);
      const float w1 = __expf(m1 - mx);       // 0 when group 1 empty (m1=-1e30)
      const float inv = 1.0f / (lrow[r] * w0 + l1 * w1);
      const size_t orow = growq + quad * 4 + r;
#pragma unroll
      for (int nt = 0; nt < 8; ++nt) {
        const float o = oacc[nt][r] * w0 + Ocmb[(size_t)row * 128 + nt * 16 + l15] * w1;
        outp[orow * 2048 + h * 128 + nt * 16 + l15] = f2bf(o * inv);
      }
    }
  }
}

extern "C" void kernel_launch(void* const* d_in, const int* in_sizes, int n_in,
                              void* d_out, int out_size, void* d_ws, size_t ws_size,
                              hipStream_t stream) {
  const float* x        = (const float*)d_in[0];
  const float* wd_q     = (const float*)d_in[1];
  const float* wu_q     = (const float*)d_in[2];
  const float* q_norm_w = (const float*)d_in[3];
  const float* wd_kv    = (const float*)d_in[4];
  const float* wu_kv    = (const float*)d_in[5];
  const float* kv_norm_w= (const float*)d_in[6];
  const float* wo       = (const float*)d_in[7];
  const float* cosb     = (const float*)d_in[8];
  const float* sinb     = (const float*)d_in[9];
  float* out = (float*)d_out;

  char* ws = (char*)d_ws;
  float*    cq    = (float*)(ws + 0);            // 4096x1536 f32 (dead after rmsnorm)
  ushort_t* q16   = (ushort_t*)(ws + 0);         // 4096x3072 bf16 (overwrites cq in q-up)
  ushort_t* kb16  = (ushort_t*)(ws + 50331648);  // 4096x2048 bf16 K rows (16MB)
  ushort_t* vT    = (ushort_t*)(ws + 67108864);  // [b*16+h][128 vd][2048 tok] bf16 (16MB)
  ushort_t* xb    = (ushort_t*)(ws + 83886080);  // 4096x2048 bf16 pre-cast x (16MB)
  ushort_t* cqn   = (ushort_t*)(ws + 117440512); // 4096x1536 bf16
  float*    kvd   = (float*)(ws + 130023424);    // 4096x640 f32 (dead after rmsnorm2)
  ushort_t* ckvn  = (ushort_t*)(ws + 140509184); // 4096x512 bf16 (dead after kvu gemm)
  ushort_t* aoutb = (ushort_t*)(ws + 130023424); // 4096x2048 bf16, aliases kvd+ckvn
  ushort_t* krope16 = (ushort_t*)(ws + 146800640); // 4096x64 bf16
  ushort_t* wdqt  = (ushort_t*)(ws + 147849216); // 1536x2048 bf16  (contiguous with ->)
  ushort_t* wdkvt = (ushort_t*)(ws + 154140672); // 640x2048 bf16   (fused B = [wdqt;wdkvt])
  ushort_t* wuqt  = (ushort_t*)(ws + 156762112); // 3072x1536 bf16
  ushort_t* wukvt = (ushort_t*)(ws + 166199296); // 4096x512 bf16
  ushort_t* wot   = (ushort_t*)(ws + 170393600); // 2048x2048 bf16

  const int M = 2 * S_LEN;  // 4096
  dim3 blk(256);
  dim3 blk512(512);

  prep_k<<<19200, blk, 0, stream>>>(x, xb, wd_q, wdqt, wd_kv, wdkvt,
                                    wu_q, wuqt, wu_kv, wukvt, wo, wot);

  mfma_gemm<2><<<dim3(2176 / 128, M / 128), blk512, 0, stream>>>(
      xb, wdqt, cq, M, 2176, 2048, 1536, nullptr, nullptr, kvd, nullptr, nullptr,
      nullptr, nullptr, nullptr);
  rmsnorm2_k<<<2 * M, 256, 0, stream>>>(cq, cqn, q_norm_w, kvd, ckvn, kv_norm_w,
                                        krope16, cosb, sinb);
  // fused q-up (768 blocks) + kv-up (1024 blocks): one 1792-block launch
  mfma_gemm<4><<<dim3(1792), blk512, 0, stream>>>(
      cqn, wuqt, nullptr, M, 0, 0, 0, q16, vT, nullptr, cosb, sinb,
      ckvn, wukvt, kb16);
  attn_k<<<2 * NHEAD * (S_LEN / QT), 1024, 0, stream>>>(q16, kb16, vT, krope16, aoutb);
  mfma_gemm<0><<<dim3(2048 / 128, M / 128), blk512, 0, stream>>>(
      aoutb, wot, out, M, 2048, 2048, 2048, nullptr, nullptr, nullptr, nullptr, nullptr,
      nullptr, nullptr, nullptr);
}

// Round 12
// 431.680 us; speedup vs baseline: 1.1144x; 1.1144x over previous
//
#include <hip/hip_runtime.h>
#include <hip/hip_bf16.h>

#define S_LEN 2048
#define NHEAD 16
#define NOPE 128
#define ROPE 64
#define HD 192   // nope + rope

typedef unsigned short ushort_t;
typedef __attribute__((ext_vector_type(8))) short short8;
typedef __attribute__((ext_vector_type(4))) float f32x4;

#define AS1 __attribute__((address_space(1)))
#define AS3 __attribute__((address_space(3)))

__device__ __forceinline__ unsigned short f2bf(float f) {
  unsigned int u = __float_as_uint(f);
  return (unsigned short)((u + 0x7FFFu + ((u >> 16) & 1u)) >> 16);
}

// ---------------- fused prep: cast x -> bf16  +  5x transpose_cast ----------------
__global__ __launch_bounds__(256) void prep_k(const float* __restrict__ x, ushort_t* __restrict__ xb,
                                              const float* __restrict__ wd_q, ushort_t* __restrict__ wdqt,
                                              const float* __restrict__ wd_kv, ushort_t* __restrict__ wdkvt,
                                              const float* __restrict__ wu_q, ushort_t* __restrict__ wuqt,
                                              const float* __restrict__ wu_kv, ushort_t* __restrict__ wukvt,
                                              const float* __restrict__ wo, ushort_t* __restrict__ wot) {
  int id = blockIdx.x;
  if (id < 4096) {
    const int i = id * 256 + threadIdx.x;
    const float4 v0 = *(const float4*)&x[(size_t)i * 8];
    const float4 v1 = *(const float4*)&x[(size_t)i * 8 + 4];
    union { uint4 u; ushort_t s[8]; } pk;
    pk.s[0] = f2bf(v0.x); pk.s[1] = f2bf(v0.y); pk.s[2] = f2bf(v0.z); pk.s[3] = f2bf(v0.w);
    pk.s[4] = f2bf(v1.x); pk.s[5] = f2bf(v1.y); pk.s[6] = f2bf(v1.z); pk.s[7] = f2bf(v1.w);
    *(uint4*)&xb[(size_t)i * 8] = pk.u;
    return;
  }
  id -= 4096;
  const float* B; ushort_t* Bt; int K, N, gx;
  if (id < 3072)               { B = wd_q;  Bt = wdqt;  K = 2048; N = 1536; gx = 48;  }
  else if ((id -= 3072) < 1280){ B = wd_kv; Bt = wdkvt; K = 2048; N = 576;  gx = 20;  }
  else if ((id -= 1280) < 4608){ B = wu_q;  Bt = wuqt;  K = 1536; N = 3072; gx = 96;  }
  else if ((id -= 4608) < 2048){ B = wu_kv; Bt = wukvt; K = 512;  N = 4096; gx = 128; }
  else { id -= 2048;             B = wo;    Bt = wot;   K = 2048; N = 2048; gx = 64;  }
  __shared__ float tile[32][33];
  const int tx = threadIdx.x & 31, ty = threadIdx.x >> 5;  // 32 x 8
  const int n0 = (id % gx) * 32, k0 = (id / gx) * 32;
  if (n0 >= N) {
#pragma unroll
    for (int r = 0; r < 4; ++r)
      Bt[(size_t)(n0 + ty + 8 * r) * K + k0 + tx] = 0;
    return;
  }
#pragma unroll
  for (int r = 0; r < 4; ++r)
    tile[ty + 8 * r][tx] = B[(size_t)(k0 + ty + 8 * r) * N + n0 + tx];
  __syncthreads();
#pragma unroll
  for (int r = 0; r < 4; ++r)
    Bt[(size_t)(n0 + ty + 8 * r) * K + k0 + tx] = f2bf(tile[tx][ty + 8 * r]);
}

// ---------------- MFMA GEMM: 512 thr / 8 waves / 128x128 tile --------------------
// Round 12: round-10 structure (double-buffer + counted vmcnt + T2 swizzle,
// SEPARATE launches — round-11's heterogeneous fusion reverted: it thrashed L2,
// FETCH 30->86MB, 368 TF) with ONE change: __launch_bounds__(512, 8) lifts the
// wave cap from 2 to 4 blocks/CU (VGPR<=64 fits, LDS 32KB allows 5) so a second
// resident block covers this block's vmcnt-wait/barrier (m114 overlap).
// EPI=0: f32 C.  EPI=1: KV split.  EPI=2: down-proj routing.  EPI=3: q-up RoPE.
template<int EPI>
__global__ __launch_bounds__(512, 8) void mfma_gemm(const ushort_t* __restrict__ A,
                                                 const ushort_t* __restrict__ Bt,
                                                 float* __restrict__ C,
                                                 int M, int N, int K, int ldc,
                                                 ushort_t* __restrict__ kb16o,
                                                 ushort_t* __restrict__ vto,
                                                 float* __restrict__ C2,
                                                 const float* __restrict__ cosb,
                                                 const float* __restrict__ sinb) {
  __shared__ ushort_t As[2][128 * 32];
  __shared__ ushort_t Bs[2][128 * 32];
  const int tid = threadIdx.x;
  const int lane = tid & 63;
  const int wave = tid >> 6;        // 0..7
  const int wm = wave & 3, wn = wave >> 2;   // 4 m-strips x 2 n-strips

  unsigned bxu = blockIdx.x, byu = blockIdx.y;
  {
    const unsigned gx = gridDim.x;
    const unsigned nwg = gx * gridDim.y;
    if ((nwg & 7u) == 0u) {
      unsigned flat = byu * gx + bxu;
      const unsigned cpx = nwg >> 3;
      flat = (flat & 7u) * cpx + (flat >> 3);
      bxu = flat % gx; byu = flat / gx;
    }
  }
  const int m0 = byu * 128, n0 = bxu * 128;
  const int l15 = lane & 15, quad = lane >> 4;

  f32x4 acc[2][4] = {};

  const int ma0 = tid >> 2;                                  // row 0..127
  const int scol = (((tid & 3) ^ ((tid >> 3) & 3)) << 3);    // swizzled src col (shorts)
  const int rsw = (l15 >> 1) & 3;                            // read-side slot XOR

  typedef AS3 ushort_t lds_us;
  lds_us* AsL = (lds_us*)As;
  lds_us* BsL = (lds_us*)Bs;
  const int wbase = wave * 512;   // shorts: 64 lanes * 8 shorts

  auto issue = [&](int k0, int buf) {
    __builtin_amdgcn_global_load_lds(
        (const AS1 void*)&A[(size_t)(m0 + ma0) * K + k0 + scol],
        (AS3 void*)(AsL + buf * 4096 + wbase), 16, 0, 0);
    __builtin_amdgcn_global_load_lds(
        (const AS1 void*)&Bt[(size_t)(n0 + ma0) * K + k0 + scol],
        (AS3 void*)(BsL + buf * 4096 + wbase), 16, 0, 0);
  };

  const int nk = K >> 5;
  issue(0, 0);
  __builtin_amdgcn_sched_barrier(0);

  for (int ks = 0; ks < nk; ++ks) {
    const int buf = ks & 1;
    const bool more = (ks + 1 < nk);
    if (more) {
      issue((ks + 1) << 5, buf ^ 1);
      __builtin_amdgcn_sched_barrier(0);
      asm volatile("s_waitcnt vmcnt(2)" ::: "memory");
    } else {
      asm volatile("s_waitcnt vmcnt(0)" ::: "memory");
    }
    __builtin_amdgcn_s_barrier();
    __builtin_amdgcn_sched_barrier(0);

    short8 af[2], bf[4];
#pragma unroll
    for (int i = 0; i < 2; ++i)
      af[i] = *(const short8*)&As[buf][(wm * 32 + i * 16 + l15) * 32 + ((quad ^ rsw) << 3)];
#pragma unroll
    for (int j = 0; j < 4; ++j)
      bf[j] = *(const short8*)&Bs[buf][(wn * 64 + j * 16 + l15) * 32 + ((quad ^ rsw) << 3)];
    __builtin_amdgcn_s_setprio(1);
#pragma unroll
    for (int i = 0; i < 2; ++i)
#pragma unroll
      for (int j = 0; j < 4; ++j)
        acc[i][j] = __builtin_amdgcn_mfma_f32_16x16x32_bf16(af[i], bf[j], acc[i][j], 0, 0, 0);
    __builtin_amdgcn_s_setprio(0);
    __builtin_amdgcn_s_barrier();
    __builtin_amdgcn_sched_barrier(0);
  }

  if constexpr (EPI == 0) {
#pragma unroll
    for (int i = 0; i < 2; ++i)
#pragma unroll
      for (int r = 0; r < 4; ++r) {
        const size_t rg = (size_t)(m0 + wm * 32 + i * 16 + quad * 4 + r);
#pragma unroll
        for (int j = 0; j < 4; ++j)
          C[rg * ldc + n0 + wn * 64 + j * 16 + l15] = acc[i][j][r];
      }
  } else if constexpr (EPI == 1) {
    const int h = n0 >> 8;
    const bool is_v = (n0 >> 7) & 1;
    if (!is_v) {
#pragma unroll
      for (int i = 0; i < 2; ++i)
#pragma unroll
        for (int r = 0; r < 4; ++r) {
          const size_t rg = (size_t)(m0 + wm * 32 + i * 16 + quad * 4 + r);
#pragma unroll
          for (int j = 0; j < 4; ++j)
            kb16o[rg * 2048 + h * 128 + wn * 64 + j * 16 + l15] = f2bf(acc[i][j][r]);
        }
    } else {
      __shared__ __align__(16) ushort_t trb[64 * 136];
      const int bb = m0 >> 11;
      const int m0loc = m0 & 2047;
      ushort_t* vbase = vto + ((size_t)(bb * NHEAD + h) * 128) * 2048;
#pragma unroll
      for (int vh = 0; vh < 2; ++vh) {
        if (wn == vh) {
#pragma unroll
          for (int i = 0; i < 2; ++i)
#pragma unroll
            for (int r = 0; r < 4; ++r) {
              const int tloc = wm * 32 + i * 16 + quad * 4 + r;   // 0..127
#pragma unroll
              for (int j = 0; j < 4; ++j)
                trb[(j * 16 + l15) * 136 + tloc] = f2bf(acc[i][j][r]);
            }
        }
        __syncthreads();
#pragma unroll
        for (int it = 0; it < 2; ++it) {
          const int u = tid + (it << 9);
          const int vdl = u >> 4, tc = u & 15;
          *(uint4*)&vbase[(size_t)(vh * 64 + vdl) * 2048 + m0loc + tc * 8] =
              *(const uint4*)&trb[vdl * 136 + tc * 8];
        }
        __syncthreads();
      }
    }
  } else if constexpr (EPI == 2) {
    float* Cd;
    int ldd, nc;
    if (n0 < 1536) { Cd = C;  ldd = 1536; nc = n0; }
    else           { Cd = C2; ldd = 640;  nc = n0 - 1536; }
#pragma unroll
    for (int i = 0; i < 2; ++i)
#pragma unroll
      for (int r = 0; r < 4; ++r) {
        const size_t rg = (size_t)(m0 + wm * 32 + i * 16 + quad * 4 + r);
#pragma unroll
        for (int j = 0; j < 4; ++j)
          Cd[rg * ldd + nc + wn * 64 + j * 16 + l15] = acc[i][j][r];
      }
  } else {  // EPI == 3: q-up epilogue: scale + RoPE + bf16 -> qo16 (kb16o arg)
    const float qscale = 0.07216878364870323f;  // 1/sqrt(192)
#pragma unroll
    for (int i = 0; i < 2; ++i)
#pragma unroll
      for (int r = 0; r < 4; ++r) {
        const int rg = m0 + wm * 32 + i * 16 + quad * 4 + r;
        const int sp = rg & (S_LEN - 1);
#pragma unroll
        for (int j = 0; j < 4; ++j) {
          const int col = n0 + wn * 64 + j * 16 + l15;
          float val = acc[i][j][r] * qscale;
          const float pr = __shfl_xor(val, 1);   // adjacent column (same row)
          const int dd = col % HD;               // 0..191 within head
          float o = val;
          if (dd >= NOPE) {
            const int d = (dd - NOPE) >> 1;
            const float cc = cosb[sp * 32 + d];
            const float sn = sinb[sp * 32 + d];
            o = (lane & 1) ? (pr * sn + val * cc) : (val * cc - pr * sn);
          }
          kb16o[(size_t)rg * 3072 + col] = f2bf(o);
        }
      }
  }
}

// ---------------- merged RMSNorm (+ fused k-rope on kv rows) ----------------
__global__ __launch_bounds__(256) void rmsnorm2_k(const float* __restrict__ cq,
                                                  ushort_t* __restrict__ cqn,
                                                  const float* __restrict__ qw,
                                                  const float* __restrict__ kvd,
                                                  ushort_t* __restrict__ ckvn,
                                                  const float* __restrict__ kvw,
                                                  ushort_t* __restrict__ krope16,
                                                  const float* __restrict__ cosb,
                                                  const float* __restrict__ sinb) {
  const bool is_q = blockIdx.x < 4096;
  const int row = blockIdx.x & 4095;
  const int tid = threadIdx.x;
  const float* ip = is_q ? cq + (size_t)row * 1536 : kvd + (size_t)row * 640;
  ushort_t* op = is_q ? cqn + (size_t)row * 1536 : ckvn + (size_t)row * 512;
  const float* w = is_q ? qw : kvw;
  const int L = is_q ? 1536 : 512;
  const int nper = L >> 8;
  float r[6];
  float ss = 0.f;
  for (int j = 0; j < nper; ++j) {
    r[j] = ip[tid + (j << 8)];
    ss += r[j] * r[j];
  }
  for (int off = 32; off; off >>= 1) ss += __shfl_down(ss, off);
  __shared__ float wsum[4];
  __shared__ float scale_s;
  if ((tid & 63) == 0) wsum[tid >> 6] = ss;
  __syncthreads();
  if (tid == 0) {
    float t = wsum[0] + wsum[1] + wsum[2] + wsum[3];
    scale_s = rsqrtf(t / (float)L + 1e-5f);
  }
  __syncthreads();
  const float sc = scale_s;
  for (int j = 0; j < nper; ++j)
    op[tid + (j << 8)] = f2bf(r[j] * sc * w[tid + (j << 8)]);
  if (!is_q && tid < 32) {           // fused k-rope (kvd cols 512..639)
    const int d = tid;
    const int s = row & (S_LEN - 1);
    const float c = cosb[s * 32 + d];
    const float sn = sinb[s * 32 + d];
    const float* kb = kvd + (size_t)row * 640 + 512;
    const float y0 = kb[2 * d], y1 = kb[2 * d + 1];
    union { unsigned int u; ushort_t s2[2]; } pk;
    pk.s2[0] = f2bf(y0 * c - y1 * sn);
    pk.s2[1] = f2bf(y0 * sn + y1 * c);
    *(unsigned int*)&krope16[(size_t)row * 64 + 2 * d] = pk.u;
  }
}

// ---------------- MFMA flash attention (round-10 split-KV, unchanged) ----------------
#define QT 128
#define KC 64
__global__ __launch_bounds__(1024, 4) void attn_k(const ushort_t* __restrict__ q16,
                                                  const ushort_t* __restrict__ kb16,
                                                  const ushort_t* __restrict__ vT,
                                                  const ushort_t* __restrict__ krope16,
                                                  ushort_t* __restrict__ outp) {
  const int bx = blockIdx.x;
  const int g = bx & 31;            // (b,h) group -> XCD g%8
  const int s = bx >> 5;            // slot 0..15
  const int tile = (s < 8) ? s : 23 - s;
  const int b = g >> 4, h = g & 15;
  const int q0 = tile * QT;
  const int tid = threadIdx.x;      // 0..1023
  const int lane = tid & 63;
  const int wv = tid >> 6;          // 0..15
  const int wg = wv >> 3;           // chunk-group 0/1
  const int wq8 = wv & 7;           // q-strip within tile
  const int gtid = tid & 511;       // thread id within group
  const int l15 = lane & 15, quad = lane >> 4;

  __shared__ __align__(16) ushort_t Kn[2][64 * 128];     // 32 KB
  __shared__ __align__(16) ushort_t Kr[2][64 * 64];      // 16 KB
  __shared__ __align__(16) ushort_t Vt[2][2][128 * 64];  // 64 KB (per-group dbuf)
  __shared__ __align__(16) ushort_t Pb[16][16 * 72];     // 36 KB

  const int qbase = q0 + wq8 * 16;  // wave's 16 q-rows
  const size_t growq = (size_t)b * S_LEN + qbase;
  const ushort_t* vTh = vT + ((size_t)(b * NHEAD + h) * 128) * 2048;
  const size_t bbase = (size_t)b * S_LEN;

  typedef AS3 ushort_t lds_us;
  lds_us* KnL = (lds_us*)Kn;
  lds_us* KrL = (lds_us*)Kr;
  lds_us* VtL = (lds_us*)Vt;

  auto issueK = [&](int c) {
    const size_t growk = bbase + (size_t)c * KC;
#pragma unroll
    for (int it = 0; it < 2; ++it) {
      const int u = gtid + (it << 9);
      const int key = u >> 4, sl = u & 15;
      const int ss = sl ^ (key & 7);
      __builtin_amdgcn_global_load_lds(
          (const AS1 void*)&kb16[(growk + key) * 2048 + h * 128 + ss * 8],
          (AS3 void*)(KnL + wg * 8192 + it * 4096 + wq8 * 512), 16, 0, 0);
    }
    {
      const int u = gtid;
      const int key = u >> 3, sl = u & 7;
      const int ss = sl ^ (key & 7);
      __builtin_amdgcn_global_load_lds(
          (const AS1 void*)&krope16[(growk + key) * 64 + ss * 8],
          (AS3 void*)(KrL + wg * 4096 + wq8 * 512), 16, 0, 0);
    }
  };
  auto issueV = [&](int c, int buf) {
    const int j0 = c * KC;
#pragma unroll
    for (int it = 0; it < 2; ++it) {
      const int u = gtid + (it << 9);
      const int vd = u >> 3, sl = u & 7;
      const int ss = sl ^ (vd & 7);
      __builtin_amdgcn_global_load_lds(
          (const AS1 void*)&vTh[(size_t)vd * 2048 + j0 + ss * 8],
          (AS3 void*)(VtL + (wg * 2 + buf) * 8192 + it * 4096 + wq8 * 512), 16, 0, 0);
    }
  };

  const int nchunk = (q0 + QT) / KC;   // 2(tile+1), always even
  const int half = nchunk >> 1;        // tile+1 chunks per group
  const int cbase = wg * half;

  // ---- prologue ----
  issueK(cbase);
  issueV(cbase, 0);
  __builtin_amdgcn_sched_barrier(0);

  short8 qf[6];
#pragma unroll
  for (int ks = 0; ks < 6; ++ks)
    qf[ks] = *(const short8*)&q16[(growq + l15) * 3072 + h * HD + ks * 32 + quad * 8];

  f32x4 oacc[8] = {};
  float mrow[4], lrow[4];
  int q_r[4];
#pragma unroll
  for (int r = 0; r < 4; ++r) {
    mrow[r] = -1e30f; lrow[r] = 0.f;
    q_r[r] = qbase + quad * 4 + r;
  }

  asm volatile("s_waitcnt vmcnt(2)" ::: "memory");   // K(c0) landed (V may fly)
  __builtin_amdgcn_s_barrier();
  __builtin_amdgcn_sched_barrier(0);

  for (int cl = 0; cl < half; ++cl) {
    const int c = cbase + cl;
    const int j0 = c * KC;
    const bool more = (cl + 1 < half);
    const int buf = cl & 1;
    const bool skipw = (j0 > qbase + 15);   // chunk fully above diagonal for this wave

    // ---- QK^T on K(c) ----
    f32x4 sacc[4] = {};
    if (!skipw) {
      __builtin_amdgcn_s_setprio(1);
#pragma unroll
      for (int ks = 0; ks < 6; ++ks) {
        short8 kf[4];
        if (ks < 4) {
#pragma unroll
          for (int kt = 0; kt < 4; ++kt)
            kf[kt] = *(const short8*)&Kn[wg][(kt * 16 + l15) * 128 + (((ks * 4 + quad) ^ (l15 & 7)) << 3)];
        } else {
#pragma unroll
          for (int kt = 0; kt < 4; ++kt)
            kf[kt] = *(const short8*)&Kr[wg][(kt * 16 + l15) * 64 + ((((ks - 4) * 4 + quad) ^ (l15 & 7)) << 3)];
        }
#pragma unroll
        for (int kt = 0; kt < 4; ++kt)
          sacc[kt] = __builtin_amdgcn_mfma_f32_16x16x32_bf16(qf[ks], kf[kt], sacc[kt], 0, 0, 0);
      }
      __builtin_amdgcn_s_setprio(0);
    }

    __builtin_amdgcn_s_barrier();          // all waves done reading their Kn/Kr
    if (more) issueK(c + 1);               // DMA into own group's Kn/Kr
    __builtin_amdgcn_sched_barrier(0);

    if (!skipw) {
      if (j0 + KC - 1 > qbase) {           // diagonal chunk: mask
#pragma unroll
        for (int kt = 0; kt < 4; ++kt) {
          const int key = j0 + kt * 16 + l15;
#pragma unroll
          for (int r = 0; r < 4; ++r)
            sacc[kt][r] = (key <= q_r[r]) ? sacc[kt][r] : -1e30f;
        }
      }
      float pmax[4];
#pragma unroll
      for (int r = 0; r < 4; ++r) {
        float mx = fmaxf(fmaxf(sacc[0][r], sacc[1][r]),
                         fmaxf(sacc[2][r], sacc[3][r]));
        mx = fmaxf(mx, __shfl_xor(mx, 1));
        mx = fmaxf(mx, __shfl_xor(mx, 2));
        mx = fmaxf(mx, __shfl_xor(mx, 4));
        mx = fmaxf(mx, __shfl_xor(mx, 8));
        pmax[r] = mx;
      }
      bool need = false;
#pragma unroll
      for (int r = 0; r < 4; ++r)
        need = need || (pmax[r] > mrow[r] + 8.0f);
      const bool upd = __any(need);
      float alpha[4];
      if (upd) {
#pragma unroll
        for (int r = 0; r < 4; ++r) {
          const float mn = fmaxf(mrow[r], pmax[r]);
          alpha[r] = __expf(mrow[r] - mn);
          mrow[r] = mn;
        }
      }
#pragma unroll
      for (int kt = 0; kt < 4; ++kt)
#pragma unroll
        for (int r = 0; r < 4; ++r)
          sacc[kt][r] = __expf(sacc[kt][r] - mrow[r]);
#pragma unroll
      for (int r = 0; r < 4; ++r) {
        float rs = sacc[0][r] + sacc[1][r] + sacc[2][r] + sacc[3][r];
        rs += __shfl_xor(rs, 1);
        rs += __shfl_xor(rs, 2);
        rs += __shfl_xor(rs, 4);
        rs += __shfl_xor(rs, 8);
        lrow[r] = upd ? lrow[r] * alpha[r] + rs : lrow[r] + rs;
      }
#pragma unroll
      for (int kt = 0; kt < 4; ++kt)
#pragma unroll
        for (int r = 0; r < 4; ++r)
          Pb[wv][(quad * 4 + r) * 72 + kt * 16 + l15] = f2bf(sacc[kt][r]);
      if (upd) {
#pragma unroll
        for (int nt = 0; nt < 8; ++nt)
#pragma unroll
          for (int r = 0; r < 4; ++r)
            oacc[nt][r] *= alpha[r];
      }
    }

    if (more) asm volatile("s_waitcnt vmcnt(3)" ::: "memory");  // V(c) landed; K(c+1) flying
    else      asm volatile("s_waitcnt vmcnt(0)" ::: "memory");
    __builtin_amdgcn_s_barrier();          // Vt[wg][buf] visible
    __builtin_amdgcn_sched_barrier(0);

    // ---- PV on Vt[wg][buf] ----
    if (!skipw) {
      __builtin_amdgcn_s_setprio(1);
#pragma unroll
      for (int st = 0; st < 2; ++st) {
        const short8 pf = *(const short8*)&Pb[wv][l15 * 72 + st * 32 + quad * 8];
#pragma unroll
        for (int nt = 0; nt < 8; ++nt) {
          const short8 vf = *(const short8*)&Vt[wg][buf][(nt * 16 + l15) * 64 + (((st * 4 + quad) ^ (l15 & 7)) << 3)];
          oacc[nt] = __builtin_amdgcn_mfma_f32_16x16x32_bf16(pf, vf, oacc[nt], 0, 0, 0);
        }
      }
      __builtin_amdgcn_s_setprio(0);
    }

    if (more) {
      issueV(c + 1, buf ^ 1);              // other buffer; no barrier needed
      __builtin_amdgcn_sched_barrier(0);
      asm volatile("s_waitcnt vmcnt(2)" ::: "memory");  // K(c+1) landed; V(c+1) flying
      __builtin_amdgcn_s_barrier();        // K(c+1) visible
      __builtin_amdgcn_sched_barrier(0);
    }
  }

  // ---- combine group 1 into group 0 (reuse K/V LDS; all DMA/PV complete) ----
  __builtin_amdgcn_s_barrier();
  float* Ocmb = (float*)&Vt[0][0][0];      // 64 KB = 8 strips x 16 rows x 128 f32
  float* Mlb  = (float*)&Kn[0][0];         // (m,l) per row
  if (wg == 1) {
#pragma unroll
    for (int nt = 0; nt < 8; ++nt)
#pragma unroll
      for (int r = 0; r < 4; ++r)
        Ocmb[(size_t)(wq8 * 16 + quad * 4 + r) * 128 + nt * 16 + l15] = oacc[nt][r];
    if (l15 == 0) {
#pragma unroll
      for (int r = 0; r < 4; ++r) {
        Mlb[(wq8 * 16 + quad * 4 + r) * 2 + 0] = mrow[r];
        Mlb[(wq8 * 16 + quad * 4 + r) * 2 + 1] = lrow[r];
      }
    }
  }
  __builtin_amdgcn_s_barrier();
  if (wg == 0) {
#pragma unroll
    for (int r = 0; r < 4; ++r) {
      const int row = wq8 * 16 + quad * 4 + r;
      const float m1 = Mlb[row * 2 + 0];
      const float l1 = Mlb[row * 2 + 1];
      const float mx = fmaxf(mrow[r], m1);
      const float w0 = __expf(mrow[r] - mx);
      const float w1 = __expf(m1 - mx);       // 0 when group 1 empty (m1=-1e30)
      const float inv = 1.0f / (lrow[r] * w0 + l1 * w1);
      const size_t orow = growq + quad * 4 + r;
#pragma unroll
      for (int nt = 0; nt < 8; ++nt) {
        const float o = oacc[nt][r] * w0 + Ocmb[(size_t)row * 128 + nt * 16 + l15] * w1;
        outp[orow * 2048 + h * 128 + nt * 16 + l15] = f2bf(o * inv);
      }
    }
  }
}

extern "C" void kernel_launch(void* const* d_in, const int* in_sizes, int n_in,
                              void* d_out, int out_size, void* d_ws, size_t ws_size,
                              hipStream_t stream) {
  const float* x        = (const float*)d_in[0];
  const float* wd_q     = (const float*)d_in[1];
  const float* wu_q     = (const float*)d_in[2];
  const float* q_norm_w = (const float*)d_in[3];
  const float* wd_kv    = (const float*)d_in[4];
  const float* wu_kv    = (const float*)d_in[5];
  const float* kv_norm_w= (const float*)d_in[6];
  const float* wo       = (const float*)d_in[7];
  const float* cosb     = (const float*)d_in[8];
  const float* sinb     = (const float*)d_in[9];
  float* out = (float*)d_out;

  char* ws = (char*)d_ws;
  float*    cq    = (float*)(ws + 0);            // 4096x1536 f32 (dead after rmsnorm)
  ushort_t* q16   = (ushort_t*)(ws + 0);         // 4096x3072 bf16 (overwrites cq in q-up)
  ushort_t* kb16  = (ushort_t*)(ws + 50331648);  // 4096x2048 bf16 K rows (16MB)
  ushort_t* vT    = (ushort_t*)(ws + 67108864);  // [b*16+h][128 vd][2048 tok] bf16 (16MB)
  ushort_t* xb    = (ushort_t*)(ws + 83886080);  // 4096x2048 bf16 pre-cast x (16MB)
  ushort_t* cqn   = (ushort_t*)(ws + 117440512); // 4096x1536 bf16
  float*    kvd   = (float*)(ws + 130023424);    // 4096x640 f32 (dead after rmsnorm2)
  ushort_t* ckvn  = (ushort_t*)(ws + 140509184); // 4096x512 bf16 (dead after kvu gemm)
  ushort_t* aoutb = (ushort_t*)(ws + 130023424); // 4096x2048 bf16, aliases kvd+ckvn
  ushort_t* krope16 = (ushort_t*)(ws + 146800640); // 4096x64 bf16
  ushort_t* wdqt  = (ushort_t*)(ws + 147849216); // 1536x2048 bf16  (contiguous with ->)
  ushort_t* wdkvt = (ushort_t*)(ws + 154140672); // 640x2048 bf16   (fused B = [wdqt;wdkvt])
  ushort_t* wuqt  = (ushort_t*)(ws + 156762112); // 3072x1536 bf16
  ushort_t* wukvt = (ushort_t*)(ws + 166199296); // 4096x512 bf16
  ushort_t* wot   = (ushort_t*)(ws + 170393600); // 2048x2048 bf16

  const int M = 2 * S_LEN;  // 4096
  dim3 blk(256);
  dim3 blk512(512);

  prep_k<<<19200, blk, 0, stream>>>(x, xb, wd_q, wdqt, wd_kv, wdkvt,
                                    wu_q, wuqt, wu_kv, wukvt, wo, wot);

  mfma_gemm<2><<<dim3(2176 / 128, M / 128), blk512, 0, stream>>>(
      xb, wdqt, cq, M, 2176, 2048, 1536, nullptr, nullptr, kvd, nullptr, nullptr);
  rmsnorm2_k<<<2 * M, 256, 0, stream>>>(cq, cqn, q_norm_w, kvd, ckvn, kv_norm_w,
                                        krope16, cosb, sinb);
  mfma_gemm<3><<<dim3(3072 / 128, M / 128), blk512, 0, stream>>>(
      cqn, wuqt, nullptr, M, 3072, 1536, 0, q16, nullptr, nullptr, cosb, sinb);
  mfma_gemm<1><<<dim3(4096 / 128, M / 128), blk512, 0, stream>>>(
      ckvn, wukvt, nullptr, M, 4096, 512, 0, kb16, vT, nullptr, nullptr, nullptr);
  attn_k<<<2 * NHEAD * (S_LEN / QT), 1024, 0, stream>>>(q16, kb16, vT, krope16, aoutb);
  mfma_gemm<0><<<dim3(2048 / 128, M / 128), blk512, 0, stream>>>(
      aoutb, wot, out, M, 2048, 2048, 2048, nullptr, nullptr, nullptr, nullptr, nullptr);
}